// Round 5
// baseline (229.264 us; speedup 1.0000x reference)
//
#include <hip/hip_runtime.h>
#include <hip/hip_bf16.h>

typedef __bf16 bf16x8 __attribute__((ext_vector_type(8)));
typedef float f32x4 __attribute__((ext_vector_type(4)));
typedef unsigned int u32x4 __attribute__((ext_vector_type(4)));

#define MFMA16(a, b, c) __builtin_amdgcn_mfma_f32_16x16x32_bf16((a), (b), (c), 0, 0, 0)
#define DEVI static __device__ __forceinline__

DEVI unsigned short f2bf(float f) {  // round-to-nearest-even fp32 -> bf16
  union { float f; unsigned u; } x; x.f = f;
  unsigned r = x.u + 0x7fffu + ((x.u >> 16) & 1u);
  return (unsigned short)(r >> 16);
}
DEVI float bf2f(unsigned short h) {
  union { unsigned u; float f; } x; x.u = ((unsigned)h) << 16;
  return x.f;
}
DEVI bf16x8 ld16(const void* p) {  // 16B aligned load (global or LDS) -> bf16x8
  u32x4 t = *reinterpret_cast<const u32x4*>(p);
  return __builtin_bit_cast(bf16x8, t);
}

// ---------- kernel 1: prep = xsplit (transpose + hi/lo split) ++ wsplit (weights)
__global__ __launch_bounds__(256) void prep_kernel(
    const float* __restrict__ x,
    const float* __restrict__ Wk, const float* __restrict__ Wq, const float* __restrict__ Wv,
    unsigned short* __restrict__ xThi, unsigned short* __restrict__ xTlo,
    unsigned short* __restrict__ Wkhi, unsigned short* __restrict__ Wklo,
    unsigned short* __restrict__ Wqhi, unsigned short* __restrict__ Wqlo,
    unsigned short* __restrict__ Wvhi, unsigned short* __restrict__ Wvlo) {
  __shared__ float xs[64][65];
  const int bid = blockIdx.x;
  const int t = threadIdx.x;
  if (bid < 512) {
    const int c0 = (bid & 7) * 64, j0 = (bid >> 3) * 64;
    {  // phase 1: coalesced row reads, f32 into LDS
      const int cr = t >> 2, jc = (t & 3) * 16;
      const float4* s4 = reinterpret_cast<const float4*>(x + (size_t)(c0 + cr) * 4096 + j0 + jc);
#pragma unroll
      for (int q = 0; q < 4; ++q) {
        float4 v = s4[q];
        xs[cr][jc + q * 4 + 0] = v.x;
        xs[cr][jc + q * 4 + 1] = v.y;
        xs[cr][jc + q * 4 + 2] = v.z;
        xs[cr][jc + q * 4 + 3] = v.w;
      }
    }
    __syncthreads();
    {  // phase 2: column reads (2-way free), split hi/lo, vector global stores
      const int jr = t >> 2, cs = (t & 3) * 16;
      unsigned short hb[16] __attribute__((aligned(16)));
      unsigned short lb[16] __attribute__((aligned(16)));
#pragma unroll
      for (int u = 0; u < 16; ++u) {
        float v = xs[cs + u][jr];
        unsigned short h = f2bf(v);
        hb[u] = h;
        lb[u] = f2bf(v - bf2f(h));
      }
      unsigned short* dh = xThi + (size_t)(j0 + jr) * 512 + c0 + cs;
      unsigned short* dl = xTlo + (size_t)(j0 + jr) * 512 + c0 + cs;
      reinterpret_cast<u32x4*>(dh)[0] = reinterpret_cast<const u32x4*>(hb)[0];
      reinterpret_cast<u32x4*>(dh)[1] = reinterpret_cast<const u32x4*>(hb)[1];
      reinterpret_cast<u32x4*>(dl)[0] = reinterpret_cast<const u32x4*>(lb)[0];
      reinterpret_cast<u32x4*>(dl)[1] = reinterpret_cast<const u32x4*>(lb)[1];
    }
  } else {
    const int nk = 64 * 512 / 4, nv = 512 * 512 / 4;
    int i = (bid - 512) * 256 + t;
    const float* in; unsigned short* hi; unsigned short* lo; int idx;
    if (i < nk)               { in = Wk; hi = Wkhi; lo = Wklo; idx = i; }
    else if (i < 2 * nk)      { in = Wq; hi = Wqhi; lo = Wqlo; idx = i - nk; }
    else if (i < 2 * nk + nv) { in = Wv; hi = Wvhi; lo = Wvlo; idx = i - 2 * nk; }
    else return;
    float4 v = reinterpret_cast<const float4*>(in)[idx];
    float vv[4] = {v.x, v.y, v.z, v.w};
    unsigned short hb[4] __attribute__((aligned(8)));
    unsigned short lb[4] __attribute__((aligned(8)));
#pragma unroll
    for (int e = 0; e < 4; ++e) { hb[e] = f2bf(vv[e]); lb[e] = f2bf(vv[e] - bf2f(hb[e])); }
    reinterpret_cast<uint2*>(hi)[idx] = *reinterpret_cast<const uint2*>(hb);
    reinterpret_cast<uint2*>(lo)[idx] = *reinterpret_cast<const uint2*>(lb);
  }
}

// ---------- kernel 2: fused projections.
// blockIdx.y < 8 : vproj c-block  (vbf[c][j], wave = 32j x 32c, block = 64j x 64c)
// blockIdx.y >= 8: kqproj mb=y-8  (kxT/qxT [4096][64] hi+lo)
__global__ __launch_bounds__(256) void proj_kernel(
    const unsigned short* __restrict__ Wkhi, const unsigned short* __restrict__ Wklo,
    const unsigned short* __restrict__ Wqhi, const unsigned short* __restrict__ Wqlo,
    const unsigned short* __restrict__ Wvhi, const unsigned short* __restrict__ Wvlo,
    const unsigned short* __restrict__ xThi, const unsigned short* __restrict__ xTlo,
    unsigned short* __restrict__ kxThi, unsigned short* __restrict__ kxTlo,
    unsigned short* __restrict__ qxThi, unsigned short* __restrict__ qxTlo,
    unsigned short* __restrict__ vbf) {
  const int y = blockIdx.y;
  const int w = threadIdx.x >> 6, lane = threadIdx.x & 63;
  const int li = lane & 15, g = lane >> 4;
  if (y < 8) {  // ---- vproj
    const int j0 = blockIdx.x * 64 + (w >> 1) * 32;
    const int c0 = y * 64 + (w & 1) * 32;
    f32x4 acc[2][2];
#pragma unroll
    for (int mf = 0; mf < 2; ++mf)
#pragma unroll
      for (int nf = 0; nf < 2; ++nf) acc[mf][nf] = f32x4{0.f, 0.f, 0.f, 0.f};
    for (int kf = 0; kf < 16; ++kf) {
      const int kk = kf * 32 + g * 8;
      bf16x8 ah[2], al[2], bh[2], bl[2];
#pragma unroll
      for (int mf = 0; mf < 2; ++mf) {
        ah[mf] = ld16(xThi + (size_t)(j0 + mf * 16 + li) * 512 + kk);
        al[mf] = ld16(xTlo + (size_t)(j0 + mf * 16 + li) * 512 + kk);
      }
#pragma unroll
      for (int nf = 0; nf < 2; ++nf) {
        bh[nf] = ld16(Wvhi + (size_t)(c0 + nf * 16 + li) * 512 + kk);
        bl[nf] = ld16(Wvlo + (size_t)(c0 + nf * 16 + li) * 512 + kk);
      }
#pragma unroll
      for (int mf = 0; mf < 2; ++mf)
#pragma unroll
        for (int nf = 0; nf < 2; ++nf) {
          acc[mf][nf] = MFMA16(ah[mf], bh[nf], acc[mf][nf]);
          acc[mf][nf] = MFMA16(ah[mf], bl[nf], acc[mf][nf]);
          acc[mf][nf] = MFMA16(al[mf], bh[nf], acc[mf][nf]);
        }
    }
#pragma unroll
    for (int mf = 0; mf < 2; ++mf)
#pragma unroll
      for (int nf = 0; nf < 2; ++nf) {
        unsigned short hv[4] __attribute__((aligned(8)));
#pragma unroll
        for (int r = 0; r < 4; ++r) hv[r] = f2bf(acc[mf][nf][r]);
        *reinterpret_cast<uint2*>(vbf + (size_t)(c0 + nf * 16 + li) * 4096 + j0 + mf * 16 + g * 4) =
            *reinterpret_cast<const uint2*>(hv);
      }
  } else {  // ---- kqproj, mb = y-8 (0..3 -> kx, 4..7 -> qx)
    const int mb = y - 8;
    const int j0 = blockIdx.x * 64 + w * 16;
    const unsigned short* Whi = (mb < 4 ? Wkhi : Wqhi) + (size_t)((mb & 3) * 16 + li) * 512 + g * 8;
    const unsigned short* Wlo = (mb < 4 ? Wklo : Wqlo) + (size_t)((mb & 3) * 16 + li) * 512 + g * 8;
    const unsigned short* Xh = xThi + (size_t)(j0 + li) * 512 + g * 8;
    const unsigned short* Xl = xTlo + (size_t)(j0 + li) * 512 + g * 8;
    f32x4 acc = f32x4{0.f, 0.f, 0.f, 0.f};
    for (int kf = 0; kf < 16; ++kf) {
      const int o = kf * 32;
      bf16x8 ah = ld16(Whi + o), al = ld16(Wlo + o);
      bf16x8 bh = ld16(Xh + o), bl = ld16(Xl + o);
      acc = MFMA16(ah, bh, acc);
      acc = MFMA16(ah, bl, acc);
      acc = MFMA16(al, bh, acc);
    }
    unsigned short hv[4] __attribute__((aligned(8))), lv[4] __attribute__((aligned(8)));
#pragma unroll
    for (int r = 0; r < 4; ++r) {
      hv[r] = f2bf(acc[r]);
      lv[r] = f2bf(acc[r] - bf2f(hv[r]));
    }
    unsigned short* oh = (mb < 4 ? kxThi : qxThi) + (size_t)(j0 + li) * 64 + (mb & 3) * 16 + g * 4;
    unsigned short* ol = (mb < 4 ? kxTlo : qxTlo) + (size_t)(j0 + li) * 64 + (mb & 3) * 16 + g * 4;
    *reinterpret_cast<uint2*>(oh) = *reinterpret_cast<const uint2*>(hv);
    *reinterpret_cast<uint2*>(ol) = *reinterpret_cast<const uint2*>(lv);
  }
}

// ---------- kernel 3: flash attention, split-KV, QBLK=64, 8 waves, j-tile=128.
// block = 512 threads; Q (hi/lo) in swizzled LDS shared by all waves.
// wave w: S^T rows j = jtile + w*16 + .. x 64 i  (24 MFMAs);
//         PV channels [w*64,(w+1)*64) x 64 i (64 MFMAs, P-frags reloaded per kf).
__global__ __launch_bounds__(512, 4) void attn_kernel(
    const unsigned short* __restrict__ kxThi, const unsigned short* __restrict__ kxTlo,
    const unsigned short* __restrict__ qxThi, const unsigned short* __restrict__ qxTlo,
    const unsigned short* __restrict__ vbf,
    unsigned short* __restrict__ pacc, float* __restrict__ pml, int split) {
  __shared__ __align__(16) unsigned short QLh[4096];  // 64 x 64 bf16, swizzled
  __shared__ __align__(16) unsigned short QLl[4096];
  __shared__ __align__(16) unsigned short PL[8192];   // 64 i x 128 j bf16, swizzled
  __shared__ __align__(16) float smax[64][8];
  __shared__ __align__(16) float ssum[64][8];
  const int jchunk = 4096 / split;
  const int s = blockIdx.x % split;            // wgid%8 = XCD -> XCD-affine j-chunk
  const int i0 = (blockIdx.x / split) * 64;
  const int jbase = s * jchunk;
  const int w = threadIdx.x >> 6, lane = threadIdx.x & 63;
  const int li = lane & 15, g = lane >> 4;
  const float L2E = 1.4426950408889634f;
  char* qlh = reinterpret_cast<char*>(QLh);
  char* qll = reinterpret_cast<char*>(QLl);
  char* plb = reinterpret_cast<char*>(PL);

  // cooperative Q stage: 64 rows x 8 chunks of 16B = 512 threads, one shot
  {
    const int row = threadIdx.x >> 3, ch = threadIdx.x & 7;
    const size_t src = (size_t)(i0 + row) * 64 + ch * 8;
    const int dst = (row * 128 + ch * 16) ^ ((row & 7) << 4);
    *reinterpret_cast<u32x4*>(qlh + dst) = *reinterpret_cast<const u32x4*>(kxThi + src);
    *reinterpret_cast<u32x4*>(qll + dst) = *reinterpret_cast<const u32x4*>(kxTlo + src);
  }
  f32x4 acc[4][4];  // [cf][f]
#pragma unroll
  for (int cf = 0; cf < 4; ++cf)
#pragma unroll
    for (int f = 0; f < 4; ++f) acc[cf][f] = f32x4{0.f, 0.f, 0.f, 0.f};
  float m_run[4] = {-3.0e38f, -3.0e38f, -3.0e38f, -3.0e38f};
  float l_run[4] = {0.f, 0.f, 0.f, 0.f};
  __syncthreads();  // Q visible

  for (int jj = 0; jj < jchunk; jj += 128) {
    const int j0 = jbase + jj;
    // --- S^T: wave w covers rows j = j0 + w*16 + (..), cols i (3-term split)
    f32x4 sc[4];
#pragma unroll
    for (int f = 0; f < 4; ++f) sc[f] = f32x4{0.f, 0.f, 0.f, 0.f};
    {
      const unsigned short* ah_p = qxThi + (size_t)(j0 + w * 16 + li) * 64 + g * 8;
      const unsigned short* al_p = qxTlo + (size_t)(j0 + w * 16 + li) * 64 + g * 8;
#pragma unroll
      for (int kf = 0; kf < 2; ++kf) {
        bf16x8 ah = ld16(ah_p + kf * 32);
        bf16x8 al = ld16(al_p + kf * 32);
#pragma unroll
        for (int f = 0; f < 4; ++f) {
          const int qb = ((f * 16 + li) * 128 + kf * 64 + g * 16) ^ ((li & 7) << 4);
          bf16x8 qh = ld16(qlh + qb);
          bf16x8 ql = ld16(qll + qb);
          sc[f] = MFMA16(ah, qh, sc[f]);
          sc[f] = MFMA16(ah, ql, sc[f]);
          sc[f] = MFMA16(al, qh, sc[f]);
        }
      }
    }
    // --- per-column (i) quadrant max -> smax[i][w]
    {
      float pm[4];
#pragma unroll
      for (int f = 0; f < 4; ++f) {
        float tm = fmaxf(fmaxf(sc[f][0], sc[f][1]), fmaxf(sc[f][2], sc[f][3]));
        tm = fmaxf(tm, __shfl_xor(tm, 16));
        tm = fmaxf(tm, __shfl_xor(tm, 32));
        pm[f] = tm;
      }
      if (lane < 16) {
#pragma unroll
        for (int f = 0; f < 4; ++f) smax[f * 16 + li][w] = pm[f];
      }
    }
    __syncthreads();  // B1
    float fac[4];
#pragma unroll
    for (int f = 0; f < 4; ++f) {
      const f32x4 s0 = *reinterpret_cast<const f32x4*>(&smax[f * 16 + li][0]);
      const f32x4 s1 = *reinterpret_cast<const f32x4*>(&smax[f * 16 + li][4]);
      const float m_new = fmaxf(m_run[f],
          fmaxf(fmaxf(fmaxf(s0[0], s0[1]), fmaxf(s0[2], s0[3])),
                fmaxf(fmaxf(s1[0], s1[1]), fmaxf(s1[2], s1[3]))));
      fac[f] = exp2f((m_run[f] - m_new) * L2E);
      m_run[f] = m_new;
    }
#pragma unroll
    for (int f = 0; f < 4; ++f) {
      float p[4];
#pragma unroll
      for (int r = 0; r < 4; ++r) p[r] = exp2f((sc[f][r] - m_run[f]) * L2E);
      float ps = (p[0] + p[1]) + (p[2] + p[3]);
      ps += __shfl_xor(ps, 16);
      ps += __shfl_xor(ps, 32);
      if (lane < 16) ssum[f * 16 + li][w] = ps;
      unsigned short pv[4] __attribute__((aligned(8)));
#pragma unroll
      for (int r = 0; r < 4; ++r) pv[r] = f2bf(p[r]);
      const int pb = ((f * 16 + li) * 256 + w * 32 + g * 8) ^ ((li & 7) << 4);
      *reinterpret_cast<uint2*>(plb + pb) = *reinterpret_cast<const uint2*>(pv);
    }
    __syncthreads();  // B2
#pragma unroll
    for (int f = 0; f < 4; ++f) {
      const f32x4 s0 = *reinterpret_cast<const f32x4*>(&ssum[f * 16 + li][0]);
      const f32x4 s1 = *reinterpret_cast<const f32x4*>(&ssum[f * 16 + li][4]);
      l_run[f] = l_run[f] * fac[f] +
          (((s0[0] + s0[1]) + (s0[2] + s0[3])) + ((s1[0] + s1[1]) + (s1[2] + s1[3])));
    }
#pragma unroll
    for (int cf = 0; cf < 4; ++cf)
#pragma unroll
      for (int f = 0; f < 4; ++f) {
#pragma unroll
        for (int r = 0; r < 4; ++r) acc[cf][f][r] *= fac[f];
      }
    // --- PV: per kf load 4 P-frags (16 regs) then 4 V rows; 16 MFMAs per kf
#pragma unroll
    for (int kf = 0; kf < 4; ++kf) {
      bf16x8 bpf[4];
#pragma unroll
      for (int f = 0; f < 4; ++f) {
        const int rb = ((f * 16 + li) * 256 + kf * 64 + g * 16) ^ ((li & 7) << 4);
        bpf[f] = ld16(plb + rb);
      }
#pragma unroll
      for (int cf = 0; cf < 4; ++cf) {
        const unsigned short* vp =
            vbf + (size_t)(w * 64 + cf * 16 + li) * 4096 + j0 + kf * 32 + g * 8;
        bf16x8 a = ld16(vp);
#pragma unroll
        for (int f = 0; f < 4; ++f) acc[cf][f] = MFMA16(a, bpf[f], acc[cf][f]);
      }
    }
    // (2 barriers/iter suffice: smax/ssum/P hazards are ordered by B1/B2 of the next iter)
  }
  // epilogue: unnormalized bf16 partials + per-row (m, l)
#pragma unroll
  for (int cf = 0; cf < 4; ++cf)
#pragma unroll
    for (int f = 0; f < 4; ++f) {
      unsigned short hv[4] __attribute__((aligned(8)));
#pragma unroll
      for (int r = 0; r < 4; ++r) hv[r] = f2bf(acc[cf][f][r]);
      unsigned short* dp = pacc + ((size_t)(s * 4096 + i0 + f * 16 + li)) * 512 + w * 64 + cf * 16 + g * 4;
      *reinterpret_cast<uint2*>(dp) = *reinterpret_cast<const uint2*>(hv);
    }
  if (w == 0 && lane < 16) {
#pragma unroll
    for (int f = 0; f < 4; ++f) {
      pml[((size_t)(s * 4096 + i0 + f * 16 + li)) * 2] = m_run[f];
      pml[((size_t)(s * 4096 + i0 + f * 16 + li)) * 2 + 1] = l_run[f];
    }
  }
}

// ---------- kernel 4: combine split partials -> out [4096][512] f32
__global__ __launch_bounds__(256) void combine_kernel(
    const unsigned short* __restrict__ pacc, const float* __restrict__ pml,
    float* __restrict__ out, int split) {
  const int t = blockIdx.x * 256 + threadIdx.x;   // 4096 * 64 threads
  const int i = t >> 6, c8 = (t & 63) << 3;
  const float L2E = 1.4426950408889634f;
  float M = -3.0e38f;
  for (int ss = 0; ss < split; ++ss) M = fmaxf(M, pml[((size_t)ss * 4096 + i) * 2]);
  float num[8];
#pragma unroll
  for (int e = 0; e < 8; ++e) num[e] = 0.f;
  float den = 0.f;
  for (int ss = 0; ss < split; ++ss) {
    const float m = pml[((size_t)ss * 4096 + i) * 2];
    const float l = pml[((size_t)ss * 4096 + i) * 2 + 1];
    const float wgt = exp2f((m - M) * L2E);
    den += wgt * l;
    u32x4 pk = *reinterpret_cast<const u32x4*>(pacc + ((size_t)ss * 4096 + i) * 512 + c8);
#pragma unroll
    for (int e = 0; e < 8; ++e) {
      unsigned short h = (unsigned short)((pk[e >> 1] >> ((e & 1) * 16)) & 0xffffu);
      num[e] += wgt * bf2f(h);
    }
  }
  const float inv = 1.0f / den;
  float4 o0, o1;
  o0.x = num[0] * inv; o0.y = num[1] * inv; o0.z = num[2] * inv; o0.w = num[3] * inv;
  o1.x = num[4] * inv; o1.y = num[5] * inv; o1.z = num[6] * inv; o1.w = num[7] * inv;
  float* op = out + (size_t)i * 512 + c8;
  *reinterpret_cast<float4*>(op) = o0;
  *reinterpret_cast<float4*>(op + 4) = o1;
}

extern "C" void kernel_launch(void* const* d_in, const int* in_sizes, int n_in,
                              void* d_out, int out_size, void* d_ws, size_t ws_size,
                              hipStream_t stream) {
  const float* x  = (const float*)d_in[0];   // [512][4096]
  const float* Wk = (const float*)d_in[1];   // [64][512]
  const float* Wq = (const float*)d_in[2];   // [64][512]
  const float* Wv = (const float*)d_in[3];   // [512][512]
  float* out = (float*)d_out;                // [4096][512]
  char* ws = (char*)d_ws;

  const size_t MB = 1024ull * 1024ull;
  const size_t pers_b = 2 * MB /*kx,qx hi/lo*/ + 4 * MB /*vbf*/;
  int split = 8;
  {
    size_t need8 = (size_t)8 * 4 * MB + 8 * 4096 * 8 + pers_b;   // ~38.3 MB
    if (ws_size < need8) split = 4;                               // ~22.2 MB
  }
  const size_t pacc_b = (size_t)split * 4 * MB;
  const size_t pml_b  = (size_t)split * 4096 * 8;

  // persistent region (live during attn): after partials
  char* pers = ws + pacc_b + pml_b;
  unsigned short* pacc  = (unsigned short*)ws;
  float*          pml   = (float*)(ws + pacc_b);
  unsigned short* kxThi = (unsigned short*)(pers + 0 * 512 * 1024);
  unsigned short* kxTlo = (unsigned short*)(pers + 1 * 512 * 1024);
  unsigned short* qxThi = (unsigned short*)(pers + 2 * 512 * 1024);
  unsigned short* qxTlo = (unsigned short*)(pers + 3 * 512 * 1024);
  unsigned short* vbf   = (unsigned short*)(pers + 4 * 512 * 1024);
  // temporaries (dead before attn) overlay the partial-acc region (pacc_b >= 9.7MB)
  unsigned short* xThi = (unsigned short*)(ws + 0 * MB);
  unsigned short* xTlo = (unsigned short*)(ws + 4 * MB);
  char* wbase = ws + 8 * MB;
  unsigned short* Wkhi = (unsigned short*)(wbase + 0 * 64 * 1024);
  unsigned short* Wklo = (unsigned short*)(wbase + 1 * 64 * 1024);
  unsigned short* Wqhi = (unsigned short*)(wbase + 2 * 64 * 1024);
  unsigned short* Wqlo = (unsigned short*)(wbase + 3 * 64 * 1024);
  unsigned short* Wvhi = (unsigned short*)(wbase + 4 * 64 * 1024);
  unsigned short* Wvlo = (unsigned short*)(wbase + 12 * 64 * 1024);
  (void)in_sizes; (void)n_in; (void)out_size;

  hipLaunchKernelGGL(prep_kernel, dim3(512 + 320), dim3(256), 0, stream,
                     x, Wk, Wq, Wv, xThi, xTlo, Wkhi, Wklo, Wqhi, Wqlo, Wvhi, Wvlo);
  hipLaunchKernelGGL(proj_kernel, dim3(64, 16), dim3(256), 0, stream,
                     Wkhi, Wklo, Wqhi, Wqlo, Wvhi, Wvlo, xThi, xTlo,
                     kxThi, kxTlo, qxThi, qxTlo, vbf);
  hipLaunchKernelGGL(attn_kernel, dim3(64 * split), dim3(512), 0, stream,
                     kxThi, kxTlo, qxThi, qxTlo, vbf, pacc, pml, split);
  hipLaunchKernelGGL(combine_kernel, dim3(1024), dim3(256), 0, stream, pacc, pml, out, split);
}

// Round 6
// 186.484 us; speedup vs baseline: 1.2294x; 1.2294x over previous
//
#include <hip/hip_runtime.h>
#include <hip/hip_bf16.h>

typedef __bf16 bf16x8 __attribute__((ext_vector_type(8)));
typedef float f32x4 __attribute__((ext_vector_type(4)));
typedef unsigned int u32x4 __attribute__((ext_vector_type(4)));

#define MFMA16(a, b, c) __builtin_amdgcn_mfma_f32_16x16x32_bf16((a), (b), (c), 0, 0, 0)
#define DEVI static __device__ __forceinline__

DEVI unsigned short f2bf(float f) {  // round-to-nearest-even fp32 -> bf16
  union { float f; unsigned u; } x; x.f = f;
  unsigned r = x.u + 0x7fffu + ((x.u >> 16) & 1u);
  return (unsigned short)(r >> 16);
}
DEVI float bf2f(unsigned short h) {
  union { unsigned u; float f; } x; x.u = ((unsigned)h) << 16;
  return x.f;
}
DEVI bf16x8 ld16(const void* p) {  // 16B aligned load (global or LDS) -> bf16x8
  u32x4 t = *reinterpret_cast<const u32x4*>(p);
  return __builtin_bit_cast(bf16x8, t);
}

// ---------- kernel 1: prep = xsplit (transpose + hi/lo split) ++ wsplit (weights)
__global__ __launch_bounds__(256) void prep_kernel(
    const float* __restrict__ x,
    const float* __restrict__ Wk, const float* __restrict__ Wq, const float* __restrict__ Wv,
    unsigned short* __restrict__ xThi, unsigned short* __restrict__ xTlo,
    unsigned short* __restrict__ Wkhi, unsigned short* __restrict__ Wklo,
    unsigned short* __restrict__ Wqhi, unsigned short* __restrict__ Wqlo,
    unsigned short* __restrict__ Wvhi, unsigned short* __restrict__ Wvlo) {
  __shared__ float xs[64][65];
  const int bid = blockIdx.x;
  const int t = threadIdx.x;
  if (bid < 512) {
    const int c0 = (bid & 7) * 64, j0 = (bid >> 3) * 64;
    {  // phase 1: coalesced row reads, f32 into LDS
      const int cr = t >> 2, jc = (t & 3) * 16;
      const float4* s4 = reinterpret_cast<const float4*>(x + (size_t)(c0 + cr) * 4096 + j0 + jc);
#pragma unroll
      for (int q = 0; q < 4; ++q) {
        float4 v = s4[q];
        xs[cr][jc + q * 4 + 0] = v.x;
        xs[cr][jc + q * 4 + 1] = v.y;
        xs[cr][jc + q * 4 + 2] = v.z;
        xs[cr][jc + q * 4 + 3] = v.w;
      }
    }
    __syncthreads();
    {  // phase 2: column reads (2-way free), split hi/lo, vector global stores
      const int jr = t >> 2, cs = (t & 3) * 16;
      unsigned short hb[16] __attribute__((aligned(16)));
      unsigned short lb[16] __attribute__((aligned(16)));
#pragma unroll
      for (int u = 0; u < 16; ++u) {
        float v = xs[cs + u][jr];
        unsigned short h = f2bf(v);
        hb[u] = h;
        lb[u] = f2bf(v - bf2f(h));
      }
      unsigned short* dh = xThi + (size_t)(j0 + jr) * 512 + c0 + cs;
      unsigned short* dl = xTlo + (size_t)(j0 + jr) * 512 + c0 + cs;
      reinterpret_cast<u32x4*>(dh)[0] = reinterpret_cast<const u32x4*>(hb)[0];
      reinterpret_cast<u32x4*>(dh)[1] = reinterpret_cast<const u32x4*>(hb)[1];
      reinterpret_cast<u32x4*>(dl)[0] = reinterpret_cast<const u32x4*>(lb)[0];
      reinterpret_cast<u32x4*>(dl)[1] = reinterpret_cast<const u32x4*>(lb)[1];
    }
  } else {
    const int nk = 64 * 512 / 4, nv = 512 * 512 / 4;
    int i = (bid - 512) * 256 + t;
    const float* in; unsigned short* hi; unsigned short* lo; int idx;
    if (i < nk)               { in = Wk; hi = Wkhi; lo = Wklo; idx = i; }
    else if (i < 2 * nk)      { in = Wq; hi = Wqhi; lo = Wqlo; idx = i - nk; }
    else if (i < 2 * nk + nv) { in = Wv; hi = Wvhi; lo = Wvlo; idx = i - 2 * nk; }
    else return;
    float4 v = reinterpret_cast<const float4*>(in)[idx];
    float vv[4] = {v.x, v.y, v.z, v.w};
    unsigned short hb[4] __attribute__((aligned(8)));
    unsigned short lb[4] __attribute__((aligned(8)));
#pragma unroll
    for (int e = 0; e < 4; ++e) { hb[e] = f2bf(vv[e]); lb[e] = f2bf(vv[e] - bf2f(hb[e])); }
    reinterpret_cast<uint2*>(hi)[idx] = *reinterpret_cast<const uint2*>(hb);
    reinterpret_cast<uint2*>(lo)[idx] = *reinterpret_cast<const uint2*>(lb);
  }
}

// ---------- kernel 2: fused projections.
// blockIdx.y < 8 : vproj c-block  (vbf[c][j], wave = 32j x 32c, block = 64j x 64c)
// blockIdx.y >= 8: kqproj mb=y-8  (kxT/qxT [4096][64] hi+lo)
__global__ __launch_bounds__(256) void proj_kernel(
    const unsigned short* __restrict__ Wkhi, const unsigned short* __restrict__ Wklo,
    const unsigned short* __restrict__ Wqhi, const unsigned short* __restrict__ Wqlo,
    const unsigned short* __restrict__ Wvhi, const unsigned short* __restrict__ Wvlo,
    const unsigned short* __restrict__ xThi, const unsigned short* __restrict__ xTlo,
    unsigned short* __restrict__ kxThi, unsigned short* __restrict__ kxTlo,
    unsigned short* __restrict__ qxThi, unsigned short* __restrict__ qxTlo,
    unsigned short* __restrict__ vbf) {
  const int y = blockIdx.y;
  const int w = threadIdx.x >> 6, lane = threadIdx.x & 63;
  const int li = lane & 15, g = lane >> 4;
  if (y < 8) {  // ---- vproj
    const int j0 = blockIdx.x * 64 + (w >> 1) * 32;
    const int c0 = y * 64 + (w & 1) * 32;
    f32x4 acc[2][2];
#pragma unroll
    for (int mf = 0; mf < 2; ++mf)
#pragma unroll
      for (int nf = 0; nf < 2; ++nf) acc[mf][nf] = f32x4{0.f, 0.f, 0.f, 0.f};
    for (int kf = 0; kf < 16; ++kf) {
      const int kk = kf * 32 + g * 8;
      bf16x8 ah[2], al[2], bh[2], bl[2];
#pragma unroll
      for (int mf = 0; mf < 2; ++mf) {
        ah[mf] = ld16(xThi + (size_t)(j0 + mf * 16 + li) * 512 + kk);
        al[mf] = ld16(xTlo + (size_t)(j0 + mf * 16 + li) * 512 + kk);
      }
#pragma unroll
      for (int nf = 0; nf < 2; ++nf) {
        bh[nf] = ld16(Wvhi + (size_t)(c0 + nf * 16 + li) * 512 + kk);
        bl[nf] = ld16(Wvlo + (size_t)(c0 + nf * 16 + li) * 512 + kk);
      }
#pragma unroll
      for (int mf = 0; mf < 2; ++mf)
#pragma unroll
        for (int nf = 0; nf < 2; ++nf) {
          acc[mf][nf] = MFMA16(ah[mf], bh[nf], acc[mf][nf]);
          acc[mf][nf] = MFMA16(ah[mf], bl[nf], acc[mf][nf]);
          acc[mf][nf] = MFMA16(al[mf], bh[nf], acc[mf][nf]);
        }
    }
#pragma unroll
    for (int mf = 0; mf < 2; ++mf)
#pragma unroll
      for (int nf = 0; nf < 2; ++nf) {
        unsigned short hv[4] __attribute__((aligned(8)));
#pragma unroll
        for (int r = 0; r < 4; ++r) hv[r] = f2bf(acc[mf][nf][r]);
        *reinterpret_cast<uint2*>(vbf + (size_t)(c0 + nf * 16 + li) * 4096 + j0 + mf * 16 + g * 4) =
            *reinterpret_cast<const uint2*>(hv);
      }
  } else {  // ---- kqproj, mb = y-8 (0..3 -> kx, 4..7 -> qx)
    const int mb = y - 8;
    const int j0 = blockIdx.x * 64 + w * 16;
    const unsigned short* Whi = (mb < 4 ? Wkhi : Wqhi) + (size_t)((mb & 3) * 16 + li) * 512 + g * 8;
    const unsigned short* Wlo = (mb < 4 ? Wklo : Wqlo) + (size_t)((mb & 3) * 16 + li) * 512 + g * 8;
    const unsigned short* Xh = xThi + (size_t)(j0 + li) * 512 + g * 8;
    const unsigned short* Xl = xTlo + (size_t)(j0 + li) * 512 + g * 8;
    f32x4 acc = f32x4{0.f, 0.f, 0.f, 0.f};
    for (int kf = 0; kf < 16; ++kf) {
      const int o = kf * 32;
      bf16x8 ah = ld16(Whi + o), al = ld16(Wlo + o);
      bf16x8 bh = ld16(Xh + o), bl = ld16(Xl + o);
      acc = MFMA16(ah, bh, acc);
      acc = MFMA16(ah, bl, acc);
      acc = MFMA16(al, bh, acc);
    }
    unsigned short hv[4] __attribute__((aligned(8))), lv[4] __attribute__((aligned(8)));
#pragma unroll
    for (int r = 0; r < 4; ++r) {
      hv[r] = f2bf(acc[r]);
      lv[r] = f2bf(acc[r] - bf2f(hv[r]));
    }
    unsigned short* oh = (mb < 4 ? kxThi : qxThi) + (size_t)(j0 + li) * 64 + (mb & 3) * 16 + g * 4;
    unsigned short* ol = (mb < 4 ? kxTlo : qxTlo) + (size_t)(j0 + li) * 64 + (mb & 3) * 16 + g * 4;
    *reinterpret_cast<uint2*>(oh) = *reinterpret_cast<const uint2*>(hv);
    *reinterpret_cast<uint2*>(ol) = *reinterpret_cast<const uint2*>(lv);
  }
}

// ---------- kernel 3: flash attention, split-KV, QBLK=64 (R3 structure: 4 waves,
// 256 threads, Q in swizzled LDS, VGPR=120 -> HW allows 4 blocks/CU; grid now
// 64 x split(16) = 1024 blocks to actually reach 4 blocks/CU).
__global__ __launch_bounds__(256, 2) void attn_kernel(
    const unsigned short* __restrict__ kxThi, const unsigned short* __restrict__ kxTlo,
    const unsigned short* __restrict__ qxThi, const unsigned short* __restrict__ qxTlo,
    const unsigned short* __restrict__ vbf,
    unsigned short* __restrict__ pacc, float* __restrict__ pml, int split) {
  __shared__ __align__(16) unsigned short QLh[4096];  // 64x64 bf16, swizzled
  __shared__ __align__(16) unsigned short QLl[4096];
  __shared__ __align__(16) unsigned short PL[4096];   // 64x64 bf16, swizzled
  __shared__ __align__(16) float smax[64][4];
  __shared__ __align__(16) float ssum[64][4];
  const int jchunk = 4096 / split;
  const int s = blockIdx.x % split;            // wgid%8 = XCD -> XCD-affine j-chunk
  const int i0 = (blockIdx.x / split) * 64;
  const int jbase = s * jchunk;
  const int w = threadIdx.x >> 6, lane = threadIdx.x & 63;
  const int li = lane & 15, g = lane >> 4;
  const float L2E = 1.4426950408889634f;
  char* qlh = reinterpret_cast<char*>(QLh);
  char* qll = reinterpret_cast<char*>(QLl);
  char* plb = reinterpret_cast<char*>(PL);

  // cooperative Q stage (kx^T rows i0..i0+63 hi/lo), swizzle ^((row&7)<<4)
  {
    const int qi = threadIdx.x >> 2;
#pragma unroll
    for (int cc = 0; cc < 2; ++cc) {
      const int ch = (threadIdx.x & 3) + cc * 4;        // 16B chunk 0..7
      const size_t src = (size_t)(i0 + qi) * 64 + ch * 8;
      const int dst = (qi * 128 + ch * 16) ^ ((qi & 7) << 4);
      *reinterpret_cast<u32x4*>(qlh + dst) = *reinterpret_cast<const u32x4*>(kxThi + src);
      *reinterpret_cast<u32x4*>(qll + dst) = *reinterpret_cast<const u32x4*>(kxTlo + src);
    }
  }
  f32x4 acc[8][4];  // [cf][if]
#pragma unroll
  for (int cf = 0; cf < 8; ++cf)
#pragma unroll
    for (int f = 0; f < 4; ++f) acc[cf][f] = f32x4{0.f, 0.f, 0.f, 0.f};
  float m_run[4] = {-3.0e38f, -3.0e38f, -3.0e38f, -3.0e38f};
  float l_run[4] = {0.f, 0.f, 0.f, 0.f};
  __syncthreads();  // Q stage visible

  for (int jj = 0; jj < jchunk; jj += 64) {
    const int j0 = jbase + jj;
    // --- S^T quadrant: rows j = j0 + w*16 + (g*4+r), cols i = f*16+li (3-term split)
    f32x4 sc[4];
#pragma unroll
    for (int f = 0; f < 4; ++f) sc[f] = f32x4{0.f, 0.f, 0.f, 0.f};
    {
      const unsigned short* ah_p = qxThi + (size_t)(j0 + w * 16 + li) * 64 + g * 8;
      const unsigned short* al_p = qxTlo + (size_t)(j0 + w * 16 + li) * 64 + g * 8;
#pragma unroll
      for (int kf = 0; kf < 2; ++kf) {
        bf16x8 ah = ld16(ah_p + kf * 32);
        bf16x8 al = ld16(al_p + kf * 32);
#pragma unroll
        for (int f = 0; f < 4; ++f) {
          const int qb = ((f * 16 + li) * 128 + kf * 64 + g * 16) ^ ((li & 7) << 4);
          bf16x8 qh = ld16(qlh + qb);
          bf16x8 ql = ld16(qll + qb);
          sc[f] = MFMA16(ah, qh, sc[f]);
          sc[f] = MFMA16(ah, ql, sc[f]);
          sc[f] = MFMA16(al, qh, sc[f]);
        }
      }
    }
    // --- per-column quadrant max -> smax[i][w]
    {
      float pm[4];
#pragma unroll
      for (int f = 0; f < 4; ++f) {
        float tm = fmaxf(fmaxf(sc[f][0], sc[f][1]), fmaxf(sc[f][2], sc[f][3]));
        tm = fmaxf(tm, __shfl_xor(tm, 16));
        tm = fmaxf(tm, __shfl_xor(tm, 32));
        pm[f] = tm;
      }
      if (lane < 16) {
#pragma unroll
        for (int f = 0; f < 4; ++f) smax[f * 16 + li][w] = pm[f];
      }
    }
    __syncthreads();  // B1
    float fac[4];
#pragma unroll
    for (int f = 0; f < 4; ++f) {
      const f32x4 sm = *reinterpret_cast<const f32x4*>(&smax[f * 16 + li][0]);
      const float m_new = fmaxf(m_run[f], fmaxf(fmaxf(sm[0], sm[1]), fmaxf(sm[2], sm[3])));
      fac[f] = exp2f((m_run[f] - m_new) * L2E);
      m_run[f] = m_new;
    }
#pragma unroll
    for (int f = 0; f < 4; ++f) {
      float p[4];
#pragma unroll
      for (int r = 0; r < 4; ++r) p[r] = exp2f((sc[f][r] - m_run[f]) * L2E);
      float ps = (p[0] + p[1]) + (p[2] + p[3]);
      ps += __shfl_xor(ps, 16);
      ps += __shfl_xor(ps, 32);
      if (lane < 16) ssum[f * 16 + li][w] = ps;
      unsigned short pv[4] __attribute__((aligned(8)));
#pragma unroll
      for (int r = 0; r < 4; ++r) pv[r] = f2bf(p[r]);
      const int pb = ((f * 16 + li) * 128 + w * 32 + g * 8) ^ ((li & 7) << 4);
      *reinterpret_cast<uint2*>(plb + pb) = *reinterpret_cast<const uint2*>(pv);
    }
    __syncthreads();  // B2
#pragma unroll
    for (int f = 0; f < 4; ++f) {
      const f32x4 ss = *reinterpret_cast<const f32x4*>(&ssum[f * 16 + li][0]);
      l_run[f] = l_run[f] * fac[f] + ((ss[0] + ss[1]) + (ss[2] + ss[3]));
    }
#pragma unroll
    for (int cf = 0; cf < 8; ++cf)
#pragma unroll
      for (int f = 0; f < 4; ++f) {
#pragma unroll
        for (int r = 0; r < 4; ++r) acc[cf][f][r] *= fac[f];
      }
    // --- PV: B = P frags from LDS, A = V rows (global, L2-resident)
    bf16x8 bp[4][2];
#pragma unroll
    for (int f = 0; f < 4; ++f)
#pragma unroll
      for (int kf = 0; kf < 2; ++kf) {
        const int rb = ((f * 16 + li) * 128 + kf * 64 + g * 16) ^ ((li & 7) << 4);
        bp[f][kf] = ld16(plb + rb);
      }
#pragma unroll
    for (int cf = 0; cf < 8; ++cf) {
      const unsigned short* vp = vbf + (size_t)(w * 128 + cf * 16 + li) * 4096 + j0 + g * 8;
      bf16x8 a0 = ld16(vp);
      bf16x8 a1 = ld16(vp + 32);
#pragma unroll
      for (int f = 0; f < 4; ++f) {
        acc[cf][f] = MFMA16(a0, bp[f][0], acc[cf][f]);
        acc[cf][f] = MFMA16(a1, bp[f][1], acc[cf][f]);
      }
    }
    // (2 barriers/iter suffice: smax writes sit behind B2(k-1); ssum/P writes behind B1(k))
  }
  // epilogue: unnormalized bf16 partials + per-row (m, l)
#pragma unroll
  for (int cf = 0; cf < 8; ++cf)
#pragma unroll
    for (int f = 0; f < 4; ++f) {
      unsigned short hv[4] __attribute__((aligned(8)));
#pragma unroll
      for (int r = 0; r < 4; ++r) hv[r] = f2bf(acc[cf][f][r]);
      unsigned short* dp = pacc + ((size_t)(s * 4096 + i0 + f * 16 + li)) * 512 + w * 128 + cf * 16 + g * 4;
      *reinterpret_cast<uint2*>(dp) = *reinterpret_cast<const uint2*>(hv);
    }
  if (w == 0 && lane < 16) {
#pragma unroll
    for (int f = 0; f < 4; ++f) {
      pml[((size_t)(s * 4096 + i0 + f * 16 + li)) * 2] = m_run[f];
      pml[((size_t)(s * 4096 + i0 + f * 16 + li)) * 2 + 1] = l_run[f];
    }
  }
}

// ---------- kernel 4: combine split partials -> out [4096][512] f32
__global__ __launch_bounds__(256) void combine_kernel(
    const unsigned short* __restrict__ pacc, const float* __restrict__ pml,
    float* __restrict__ out, int split) {
  const int t = blockIdx.x * 256 + threadIdx.x;   // 4096 * 64 threads
  const int i = t >> 6, c8 = (t & 63) << 3;
  const float L2E = 1.4426950408889634f;
  float M = -3.0e38f;
  for (int ss = 0; ss < split; ++ss) M = fmaxf(M, pml[((size_t)ss * 4096 + i) * 2]);
  float num[8];
#pragma unroll
  for (int e = 0; e < 8; ++e) num[e] = 0.f;
  float den = 0.f;
  for (int ss = 0; ss < split; ++ss) {
    const float m = pml[((size_t)ss * 4096 + i) * 2];
    const float l = pml[((size_t)ss * 4096 + i) * 2 + 1];
    const float wgt = exp2f((m - M) * L2E);
    den += wgt * l;
    u32x4 pk = *reinterpret_cast<const u32x4*>(pacc + ((size_t)ss * 4096 + i) * 512 + c8);
#pragma unroll
    for (int e = 0; e < 8; ++e) {
      unsigned short h = (unsigned short)((pk[e >> 1] >> ((e & 1) * 16)) & 0xffffu);
      num[e] += wgt * bf2f(h);
    }
  }
  const float inv = 1.0f / den;
  float4 o0, o1;
  o0.x = num[0] * inv; o0.y = num[1] * inv; o0.z = num[2] * inv; o0.w = num[3] * inv;
  o1.x = num[4] * inv; o1.y = num[5] * inv; o1.z = num[6] * inv; o1.w = num[7] * inv;
  float* op = out + (size_t)i * 512 + c8;
  *reinterpret_cast<float4*>(op) = o0;
  *reinterpret_cast<float4*>(op + 4) = o1;
}

extern "C" void kernel_launch(void* const* d_in, const int* in_sizes, int n_in,
                              void* d_out, int out_size, void* d_ws, size_t ws_size,
                              hipStream_t stream) {
  const float* x  = (const float*)d_in[0];   // [512][4096]
  const float* Wk = (const float*)d_in[1];   // [64][512]
  const float* Wq = (const float*)d_in[2];   // [64][512]
  const float* Wv = (const float*)d_in[3];   // [512][512]
  float* out = (float*)d_out;                // [4096][512]
  char* ws = (char*)d_ws;

  const size_t MB = 1024ull * 1024ull;
  const size_t pers_b = 2 * MB /*kx,qx hi/lo*/ + 4 * MB /*vbf*/;
  // split-KV factor: prefer 16 (grid 1024 -> 4 blocks/CU), fallback on ws_size
  int split = 16;
  {
    size_t need16 = (size_t)16 * 4 * MB + (size_t)16 * 4096 * 8 + pers_b;  // ~70.5 MB
    size_t need8  = (size_t)8  * 4 * MB + (size_t)8  * 4096 * 8 + pers_b;  // ~38.3 MB
    if (ws_size < need16) split = 8;
    if (ws_size < need8)  split = 4;
  }
  const size_t pacc_b = (size_t)split * 4 * MB;
  const size_t pml_b  = (size_t)split * 4096 * 8;

  // persistent region (live during attn): after partials
  char* pers = ws + pacc_b + pml_b;
  unsigned short* pacc  = (unsigned short*)ws;
  float*          pml   = (float*)(ws + pacc_b);
  unsigned short* kxThi = (unsigned short*)(pers + 0 * 512 * 1024);
  unsigned short* kxTlo = (unsigned short*)(pers + 1 * 512 * 1024);
  unsigned short* qxThi = (unsigned short*)(pers + 2 * 512 * 1024);
  unsigned short* qxTlo = (unsigned short*)(pers + 3 * 512 * 1024);
  unsigned short* vbf   = (unsigned short*)(pers + 4 * 512 * 1024);
  // temporaries (dead before attn) overlay the partial-acc region (pacc_b >= 9.7MB)
  unsigned short* xThi = (unsigned short*)(ws + 0 * MB);
  unsigned short* xTlo = (unsigned short*)(ws + 4 * MB);
  char* wbase = ws + 8 * MB;
  unsigned short* Wkhi = (unsigned short*)(wbase + 0 * 64 * 1024);
  unsigned short* Wklo = (unsigned short*)(wbase + 1 * 64 * 1024);
  unsigned short* Wqhi = (unsigned short*)(wbase + 2 * 64 * 1024);
  unsigned short* Wqlo = (unsigned short*)(wbase + 3 * 64 * 1024);
  unsigned short* Wvhi = (unsigned short*)(wbase + 4 * 64 * 1024);
  unsigned short* Wvlo = (unsigned short*)(wbase + 12 * 64 * 1024);
  (void)in_sizes; (void)n_in; (void)out_size;

  hipLaunchKernelGGL(prep_kernel, dim3(512 + 320), dim3(256), 0, stream,
                     x, Wk, Wq, Wv, xThi, xTlo, Wkhi, Wklo, Wqhi, Wqlo, Wvhi, Wvlo);
  hipLaunchKernelGGL(proj_kernel, dim3(64, 16), dim3(256), 0, stream,
                     Wkhi, Wklo, Wqhi, Wqlo, Wvhi, Wvlo, xThi, xTlo,
                     kxThi, kxTlo, qxThi, qxTlo, vbf);
  hipLaunchKernelGGL(attn_kernel, dim3(64 * split), dim3(256), 0, stream,
                     kxThi, kxTlo, qxThi, qxTlo, vbf, pacc, pml, split);
  hipLaunchKernelGGL(combine_kernel, dim3(1024), dim3(256), 0, stream, pacc, pml, out, split);
}